// Round 1
// baseline (191.135 us; speedup 1.0000x reference)
//
#include <hip/hip_runtime.h>

#define B_N 32768
#define D 512
#define DD (D * D)
#define NLEV 10
#define ALIGN 64                  // level-segment alignment (was 128)
#define NHB 128                   // histogram blocks (B_N / 256)
#define MROWS_MAX 34048           // perm buffer headroom (>= 32768 + 10*64)
#define TNB 128                   // cols per k3 block
#define NCT (D / TNB)             // 4 col tiles
#define NRG 64                    // row groups -> 4*64 = 256 blocks = 1/CU

typedef unsigned short u16;
typedef short s16x8 __attribute__((ext_vector_type(8)));
typedef u16 u16x8 __attribute__((ext_vector_type(8)));
typedef float f32x4 __attribute__((ext_vector_type(4)));

__device__ __forceinline__ u16 f2bf(float f) {
  union { float f; unsigned u; } v; v.f = f;
  unsigned r = v.u + 0x7fffu + ((v.u >> 16) & 1u);  // RNE
  return (u16)(r >> 16);
}
__device__ __forceinline__ int clampv(int v) {
  return v < 0 ? 0 : (v > NLEV - 1 ? NLEV - 1 : v);
}

// ---- K1: weff-build (blocks 0..1023) UNION hist+perm-fill (blocks 1024..1151)
__global__ void k1(const float* __restrict__ W, const float* __restrict__ lg,
                   const float* __restrict__ attn, const int* __restrict__ val,
                   u16* __restrict__ weff, u16* __restrict__ hist,
                   int* __restrict__ perm) {
  const int t = threadIdx.x;
  if (blockIdx.x < DD / 256) {
    __shared__ float c[NLEV * NLEV];
    if (t < NLEV) {
      float g[NLEV], a[NLEV], mx = -1e30f;
      #pragma unroll
      for (int l = 0; l < NLEV; ++l) {
        g[l] = 1.0f / (1.0f + expf(-lg[l]));
        a[l] = attn[t * NLEV + l];
        mx = fmaxf(mx, a[l]);
      }
      float s = 0.f;
      #pragma unroll
      for (int l = 0; l < NLEV; ++l) { a[l] = expf(a[l] - mx); s += a[l]; }
      float inv = 1.0f / s;
      #pragma unroll
      for (int l = 0; l < NLEV; ++l) {
        float cc = 0.3f * a[l] * inv * g[l];
        if (l == t) cc += 0.7f * g[t];
        c[t * NLEV + l] = cc;
      }
    }
    __syncthreads();
    const int idx = blockIdx.x * 256 + t;
    float w[NLEV];
    #pragma unroll
    for (int l = 0; l < NLEV; ++l) w[l] = W[l * DD + idx];
    #pragma unroll
    for (int v = 0; v < NLEV; ++v) {
      float s = 0.f;
      #pragma unroll
      for (int l = 0; l < NLEV; ++l) s += c[v * NLEV + l] * w[l];
      weff[v * DD + idx] = f2bf(s);
    }
  } else {
    __shared__ int lc[NLEV];
    const int b = blockIdx.x - DD / 256;   // 0..127
    if (t < NLEV) lc[t] = 0;
    __syncthreads();
    const int gid = b * 256 + t;
    atomicAdd(&lc[clampv(val[gid])], 1);
    perm[gid] = -1;
    if (b < (MROWS_MAX - B_N) / 256) perm[B_N + b * 256 + t] = -1;
    __syncthreads();
    if (t < NLEV) hist[b * NLEV + t] = (u16)lc[t];
  }
}

// ---- K2: deterministic counting-sort scatter (prefix over hist table) ------
__global__ void k2(const int* __restrict__ val, const u16* __restrict__ hist,
                   int* __restrict__ perm, int* __restrict__ starts) {
  __shared__ int h[NHB * NLEV];
  __shared__ int st[NLEV + 1];
  __shared__ int cnt[NLEV];
  __shared__ int lc[NLEV];
  const int t = threadIdx.x, b = blockIdx.x;
  for (int i = t; i < NHB * NLEV; i += 256) h[i] = hist[i];
  if (t < NLEV) lc[t] = 0;
  __syncthreads();
  if (t < NLEV) {
    int run = 0;
    for (int bb = 0; bb < NHB; ++bb) {
      int x = h[bb * NLEV + t];
      h[bb * NLEV + t] = run;
      run += x;
    }
    cnt[t] = run;
  }
  __syncthreads();
  if (t == 0) {
    int s = 0;
    for (int v = 0; v < NLEV; ++v) {
      st[v] = s;
      s += (cnt[v] + ALIGN - 1) & ~(ALIGN - 1);
    }
    st[NLEV] = s;
  }
  __syncthreads();
  const int gid = b * 256 + t;
  const int v = clampv(val[gid]);
  const int pos = atomicAdd(&lc[v], 1);
  perm[st[v] + h[b * NLEV + v] + pos] = gid;
  if (b == 0 && t <= NLEV) starts[t] = st[t];
}

// ---- K3: B-resident streaming GEMM -----------------------------------------
// 256 blocks (4 col-tiles x 64 row-groups), 8 waves each. Per level segment:
// stage the whole 128x512 bf16 weff panel into LDS ONCE (128 KB), then each
// wave streams independent 64-row strips with NO barriers: A frags converted
// inline from global x (fp32->bf16), B frags from swizzled resident LDS,
// 1-step register prefetch on A. No per-K-step vmcnt(0)+barrier drain.
__global__ __launch_bounds__(512) void k3(
    const float* __restrict__ x, const u16* __restrict__ weff,
    const int* __restrict__ perm, const int* __restrict__ starts,
    const float* __restrict__ bias, float* __restrict__ out) {
  __shared__ u16 Bs[TNB * D];   // 128 KB, chunk layout: [n][kc^(n&7)] 16B chunks

  const int ct = blockIdx.x;    // 0..3
  const int rg = blockIdx.y;    // 0..63
  const int tid = threadIdx.x;
  const int lane = tid & 63, wv = tid >> 6;
  const int fm = lane & 15, cb = lane >> 4;   // frag row/col, k-chunk

  int st[NLEV + 1];
  #pragma unroll
  for (int i = 0; i <= NLEV; ++i) st[i] = starts[i];
  const int Mpad = st[NLEV];
  const int ts = Mpad >> 6;                 // 64-row strips total
  const int q = ts >> 6, r = ts & 63;       // fair split over 64 row groups
  const int s0 = rg < r ? rg * (q + 1) : r * (q + 1) + (rg - r) * q;
  const int nst = rg < r ? q + 1 : q;
  if (nst <= 0) return;
  const int row0 = s0 << 6, row1 = (s0 + nst) << 6;

  float bv[8];
  #pragma unroll
  for (int nf = 0; nf < 8; ++nf) bv[nf] = bias[ct * TNB + nf * 16 + fm];

  const u16* wct = weff + (size_t)ct * TNB * D;

  for (int v = 0; v < NLEV; ++v) {
    const int seg0 = row0 > st[v] ? row0 : st[v];
    const int seg1 = row1 < st[v + 1] ? row1 : st[v + 1];
    if (seg0 >= seg1) continue;

    // ---- stage B(v, ct): linear LDS dst + inverse-swizzled global src ----
    __syncthreads();   // prior segment's ds_reads done before overwrite
    const u16* wb = wct + (size_t)v * DD;
    #pragma unroll
    for (int i = 0; i < 16; ++i) {
      const int cid = i * 512 + tid;        // wave-linear 16B chunk id
      const int n = cid >> 6, kc = cid & 63;
      const int kcs = kc ^ (n & 7);         // pre-swizzle the SOURCE
      __builtin_amdgcn_global_load_lds(
          (const __attribute__((address_space(1))) void*)(wb + n * D + kcs * 8),
          (__attribute__((address_space(3))) void*)(Bs + cid * 8), 16, 0, 0);
    }
    __syncthreads();   // implies vmcnt(0) drain of the staging loads

    const int ns = (seg1 - seg0) >> 6;
    for (int si = wv; si < ns; si += 8) {   // waves fully independent here
      const int srow = seg0 + (si << 6);

      const float* xb[4];
      #pragma unroll
      for (int m = 0; m < 4; ++m) {
        const int p = perm[srow + m * 16 + fm];
        xb[m] = x + (size_t)(p < 0 ? 0 : p) * D + cb * 8;
      }

      f32x4 acc[4][8];
      #pragma unroll
      for (int m = 0; m < 4; ++m)
        #pragma unroll
        for (int nf = 0; nf < 8; ++nf) acc[m][nf] = (f32x4){0.f, 0.f, 0.f, 0.f};

      // prefetch k=0
      f32x4 p0[4], p1[4];
      #pragma unroll
      for (int m = 0; m < 4; ++m) {
        const f32x4* qp = (const f32x4*)xb[m];
        p0[m] = qp[0]; p1[m] = qp[1];
      }

      for (int k = 0; k < D / 32; ++k) {
        s16x8 af[4];
        #pragma unroll
        for (int m = 0; m < 4; ++m) {
          u16x8 cc;
          #pragma unroll
          for (int qq = 0; qq < 4; ++qq) {
            cc[qq] = f2bf(p0[m][qq]); cc[4 + qq] = f2bf(p1[m][qq]);
          }
          af[m] = (s16x8)cc;
        }
        if (k < D / 32 - 1) {               // issue next A loads before MFMAs
          #pragma unroll
          for (int m = 0; m < 4; ++m) {
            const f32x4* qp = (const f32x4*)(xb[m] + (k + 1) * 32);
            p0[m] = qp[0]; p1[m] = qp[1];
          }
        }
        s16x8 bf[8];
        #pragma unroll
        for (int nf = 0; nf < 8; ++nf) {
          const int n = nf * 16 + fm;
          const int chunk = (n << 6) + ((k * 4 + cb) ^ (fm & 7));
          bf[nf] = *(const s16x8*)(Bs + chunk * 8);
        }
        #pragma unroll
        for (int m = 0; m < 4; ++m)
          #pragma unroll
          for (int nf = 0; nf < 8; ++nf)
            acc[m][nf] = __builtin_amdgcn_mfma_f32_16x16x32_bf16(
                af[m], bf[nf], acc[m][nf], 0, 0, 0);
      }

      // epilogue: C frag col=lane&15, row=(lane>>4)*4+reg
      #pragma unroll
      for (int m = 0; m < 4; ++m) {
        #pragma unroll
        for (int rr = 0; rr < 4; ++rr) {
          const int p2 = perm[srow + m * 16 + cb * 4 + rr];
          if (p2 >= 0) {
            float* o = out + (size_t)p2 * D + ct * TNB + fm;
            #pragma unroll
            for (int nf = 0; nf < 8; ++nf)
              o[nf * 16] = acc[m][nf][rr] + bv[nf];
          }
        }
      }
    }
  }
}

extern "C" void kernel_launch(void* const* d_in, const int* in_sizes, int n_in,
                              void* d_out, int out_size, void* d_ws, size_t ws_size,
                              hipStream_t stream) {
  const float* x    = (const float*)d_in[0];
  const int*   val  = (const int*)d_in[1];
  const float* W    = (const float*)d_in[2];
  const float* lg   = (const float*)d_in[3];
  const float* attn = (const float*)d_in[4];
  const float* bias = (const float*)d_in[5];
  float* out = (float*)d_out;

  char* ws = (char*)d_ws;
  int* starts = (int*)(ws + 0);          // 11 ints
  u16* hist   = (u16*)(ws + 64);         // 128*10 u16
  int* perm   = (int*)(ws + 2688);       // 34048 ints -> ends 138880
  u16* weff   = (u16*)(ws + 139264);     // 10*512*512 bf16 = 5.24 MB

  k1<<<DD / 256 + NHB, 256, 0, stream>>>(W, lg, attn, val, weff, hist, perm);
  k2<<<NHB, 256, 0, stream>>>(val, hist, perm, starts);
  k3<<<dim3(NCT, NRG), 512, 0, stream>>>(x, weff, perm, starts, bias, out);
}

// Round 2
// 186.617 us; speedup vs baseline: 1.0242x; 1.0242x over previous
//
#include <hip/hip_runtime.h>

#define B_N 32768
#define D 512
#define DD (D * D)
#define NLEV 10
#define TM 128
#define TN 128
#define BK 32
#define NITER (D / BK)            // 16
#define NHB 128                   // histogram blocks (B_N / 256)
#define MROWS_MAX 34048           // 32768 + 10*128 padding headroom
#define MAX_RT (MROWS_MAX / TM)   // 266

typedef unsigned short u16;
typedef short s16x8 __attribute__((ext_vector_type(8)));
typedef u16 u16x8 __attribute__((ext_vector_type(8)));
typedef float f32x4 __attribute__((ext_vector_type(4)));

__device__ __forceinline__ u16 f2bf(float f) {
  union { float f; unsigned u; } v; v.f = f;
  unsigned r = v.u + 0x7fffu + ((v.u >> 16) & 1u);  // RNE
  return (u16)(r >> 16);
}
__device__ __forceinline__ int clampv(int v) {
  return v < 0 ? 0 : (v > NLEV - 1 ? NLEV - 1 : v);
}

// ---- K1: weff-build (blocks 0..1023) UNION hist+perm-fill (blocks 1024..1151)
__global__ void k1(const float* __restrict__ W, const float* __restrict__ lg,
                   const float* __restrict__ attn, const int* __restrict__ val,
                   u16* __restrict__ weff, u16* __restrict__ hist,
                   int* __restrict__ perm) {
  const int t = threadIdx.x;
  if (blockIdx.x < DD / 256) {
    __shared__ float c[NLEV * NLEV];
    if (t < NLEV) {
      float g[NLEV], a[NLEV], mx = -1e30f;
      #pragma unroll
      for (int l = 0; l < NLEV; ++l) {
        g[l] = 1.0f / (1.0f + expf(-lg[l]));
        a[l] = attn[t * NLEV + l];
        mx = fmaxf(mx, a[l]);
      }
      float s = 0.f;
      #pragma unroll
      for (int l = 0; l < NLEV; ++l) { a[l] = expf(a[l] - mx); s += a[l]; }
      float inv = 1.0f / s;
      #pragma unroll
      for (int l = 0; l < NLEV; ++l) {
        float cc = 0.3f * a[l] * inv * g[l];
        if (l == t) cc += 0.7f * g[t];
        c[t * NLEV + l] = cc;
      }
    }
    __syncthreads();
    const int idx = blockIdx.x * 256 + t;
    float w[NLEV];
    #pragma unroll
    for (int l = 0; l < NLEV; ++l) w[l] = W[l * DD + idx];
    #pragma unroll
    for (int v = 0; v < NLEV; ++v) {
      float s = 0.f;
      #pragma unroll
      for (int l = 0; l < NLEV; ++l) s += c[v * NLEV + l] * w[l];
      weff[v * DD + idx] = f2bf(s);
    }
  } else {
    __shared__ int lc[NLEV];
    const int b = blockIdx.x - DD / 256;   // 0..127
    if (t < NLEV) lc[t] = 0;
    __syncthreads();
    const int gid = b * 256 + t;
    atomicAdd(&lc[clampv(val[gid])], 1);
    perm[gid] = -1;
    if (b < (MROWS_MAX - B_N) / 256) perm[B_N + b * 256 + t] = -1;
    __syncthreads();
    if (t < NLEV) hist[b * NLEV + t] = (u16)lc[t];
  }
}

// ---- K2: deterministic counting-sort scatter (prefix over hist table) ------
__global__ void k2(const int* __restrict__ val, const u16* __restrict__ hist,
                   int* __restrict__ perm, int* __restrict__ starts) {
  __shared__ int h[NHB * NLEV];
  __shared__ int st[NLEV + 1];
  __shared__ int cnt[NLEV];
  __shared__ int lc[NLEV];
  const int t = threadIdx.x, b = blockIdx.x;
  for (int i = t; i < NHB * NLEV; i += 256) h[i] = hist[i];
  if (t < NLEV) lc[t] = 0;
  __syncthreads();
  if (t < NLEV) {
    int run = 0;
    for (int bb = 0; bb < NHB; ++bb) {
      int x = h[bb * NLEV + t];
      h[bb * NLEV + t] = run;
      run += x;
    }
    cnt[t] = run;
  }
  __syncthreads();
  if (t == 0) {
    int s = 0;
    for (int v = 0; v < NLEV; ++v) {
      st[v] = s;
      s += (cnt[v] + TM - 1) & ~(TM - 1);
    }
    st[NLEV] = s;
  }
  __syncthreads();
  const int gid = b * 256 + t;
  const int v = clampv(val[gid]);
  const int pos = atomicAdd(&lc[v], 1);
  perm[st[v] + h[b * NLEV + v] + pos] = gid;
  if (b == 0 && t <= NLEV) starts[t] = st[t];
}

// ---- K3: grouped GEMM, 128x128 tile, 256 threads, double-buffered K-loop ---
// Same proven inner structure as the 67.7us version; tile halved so the grid
// provides 1044 blocks = 4.08 blocks/CU (was 2.04, grid-limited occupancy).
__global__ __launch_bounds__(256, 4) void k3(
    const float* __restrict__ x, const u16* __restrict__ weff,
    const int* __restrict__ perm, const int* __restrict__ starts,
    const float* __restrict__ bias, float* __restrict__ out) {
  __shared__ u16 As[2][TM * BK];   // 2 x 8 KB
  __shared__ u16 Bs[2][TN * BK];   // 2 x 8 KB

  const int ct = blockIdx.x, rt = blockIdx.y;
  const int Mpad = starts[NLEV];
  if (rt * TM >= Mpad) return;

  int v = 0;
  #pragma unroll
  for (int i = 1; i < NLEV; ++i) if (rt * TM >= starts[i]) v = i;

  const int tid = threadIdx.x;            // 0..255
  const int lane = tid & 63, wave = tid >> 6;   // 4 waves
  const int wm = (wave >> 1) * 64, wn = (wave & 1) * 64;
  const int fm = lane & 15;
  const int cb = lane >> 4;

  // A staging: 2 threads per row, 2 chunks (16 consecutive floats) each
  const int ar = tid >> 1;       // 0..127
  const int ah0 = (tid & 1) * 2; // chunks ah0, ah0+1
  int prow = perm[rt * TM + ar];
  if (prow < 0) prow = 0;
  const float* xrow = x + (size_t)prow * D + ah0 * 8;
  const int sw = (ar >> 1) & 3;
  const int aslot0 = ar * BK + (((ah0    ) ^ sw) << 3);
  const int aslot1 = ar * BK + (((ah0 + 1) ^ sw) << 3);

  const u16* wb = weff + ((size_t)v * D + ct * TN) * D;
  // B staging: 512 chunks of 16B, 2 per thread, swizzled at source
  const int c0i = tid;                         // wave*64 + lane
  const int c1i = 256 + tid;
  const int n0 = c0i >> 2, s0 = c0i & 3, kc0 = s0 ^ ((n0 >> 1) & 3);
  const int n1 = c1i >> 2, s1 = c1i & 3, kc1 = s1 ^ ((n1 >> 1) & 3);
  const u16* gb0 = wb + n0 * D + kc0 * 8;
  const u16* gb1 = wb + n1 * D + kc1 * 8;
  const int bdst0 = c0i * 8, bdst1 = c1i * 8;

  f32x4 acc[4][4];
  #pragma unroll
  for (int i = 0; i < 4; ++i)
    #pragma unroll
    for (int j = 0; j < 4; ++j) acc[i][j] = (f32x4){0.f, 0.f, 0.f, 0.f};

  // ---- prologue: stage iter 0, reg-prefetch x for iter 1 ----
  {
    __builtin_amdgcn_global_load_lds(
        (const __attribute__((address_space(1))) void*)gb0,
        (__attribute__((address_space(3))) void*)(Bs[0] + bdst0), 16, 0, 0);
    __builtin_amdgcn_global_load_lds(
        (const __attribute__((address_space(1))) void*)gb1,
        (__attribute__((address_space(3))) void*)(Bs[0] + bdst1), 16, 0, 0);
    const f32x4* xp = (const f32x4*)xrow;
    f32x4 f0 = xp[0], f1 = xp[1], f2 = xp[2], f3 = xp[3];
    u16x8 cA, cB;
    #pragma unroll
    for (int q = 0; q < 4; ++q) {
      cA[q] = f2bf(f0[q]); cA[4 + q] = f2bf(f1[q]);
      cB[q] = f2bf(f2[q]); cB[4 + q] = f2bf(f3[q]);
    }
    *(u16x8*)(As[0] + aslot0) = cA;
    *(u16x8*)(As[0] + aslot1) = cB;
  }
  f32x4 cf0, cf1, cf2, cf3;   // x data for iter i+1 (loaded 2 iters ahead)
  {
    const f32x4* xp = (const f32x4*)(xrow + BK);
    cf0 = xp[0]; cf1 = xp[1]; cf2 = xp[2]; cf3 = xp[3];
  }
  __syncthreads();

  int p = 0;
  for (int i = 0; i < NITER; ++i) {
    const bool hn = (i + 1 < NITER);
    // issue B prefetch for iter i+1 into buffer p^1
    if (hn) {
      const int k1o = (i + 1) * BK;
      __builtin_amdgcn_global_load_lds(
          (const __attribute__((address_space(1))) void*)(gb0 + k1o),
          (__attribute__((address_space(3))) void*)(Bs[p ^ 1] + bdst0), 16, 0, 0);
      __builtin_amdgcn_global_load_lds(
          (const __attribute__((address_space(1))) void*)(gb1 + k1o),
          (__attribute__((address_space(3))) void*)(Bs[p ^ 1] + bdst1), 16, 0, 0);
    }
    // issue x load for iter i+2
    f32x4 nf0, nf1, nf2, nf3;
    if (i + 2 < NITER) {
      const f32x4* xp = (const f32x4*)(xrow + (i + 2) * BK);
      nf0 = xp[0]; nf1 = xp[1]; nf2 = xp[2]; nf3 = xp[3];
    }
    // compute on buffer p (overlaps in-flight loads)
    s16x8 af[4], bf[4];
    #pragma unroll
    for (int t4 = 0; t4 < 4; ++t4) {
      const int m = wm + t4 * 16 + fm;
      af[t4] = *(const s16x8*)(As[p] + m * BK + ((cb ^ ((m >> 1) & 3)) << 3));
      const int n = wn + t4 * 16 + fm;
      bf[t4] = *(const s16x8*)(Bs[p] + n * BK + ((cb ^ ((n >> 1) & 3)) << 3));
    }
    #pragma unroll
    for (int tm = 0; tm < 4; ++tm)
      #pragma unroll
      for (int tn = 0; tn < 4; ++tn)
        acc[tm][tn] = __builtin_amdgcn_mfma_f32_16x16x32_bf16(af[tm], bf[tn], acc[tm][tn], 0, 0, 0);
    // convert + LDS-write the x chunks for iter i+1 (loaded 2 iters ago)
    if (hn) {
      u16x8 cA, cB;
      #pragma unroll
      for (int q = 0; q < 4; ++q) {
        cA[q] = f2bf(cf0[q]); cA[4 + q] = f2bf(cf1[q]);
        cB[q] = f2bf(cf2[q]); cB[4 + q] = f2bf(cf3[q]);
      }
      *(u16x8*)(As[p ^ 1] + aslot0) = cA;
      *(u16x8*)(As[p ^ 1] + aslot1) = cB;
      cf0 = nf0; cf1 = nf1; cf2 = nf2; cf3 = nf3;
    }
    __syncthreads();
    p ^= 1;
  }

  // Epilogue: C frag col=lane&15, row=(lane>>4)*4+reg; scatter rows via perm
  float bv[4];
  #pragma unroll
  for (int tn = 0; tn < 4; ++tn) bv[tn] = bias[ct * TN + wn + tn * 16 + fm];
  #pragma unroll
  for (int tm = 0; tm < 4; ++tm) {
    #pragma unroll
    for (int r = 0; r < 4; ++r) {
      const int mrow = wm + tm * 16 + (lane >> 4) * 4 + r;
      const int p2 = perm[rt * TM + mrow];
      if (p2 >= 0) {
        float* o = out + (size_t)p2 * D + ct * TN + wn + fm;
        #pragma unroll
        for (int tn = 0; tn < 4; ++tn)
          o[tn * 16] = acc[tm][tn][r] + bv[tn];
      }
    }
  }
}

extern "C" void kernel_launch(void* const* d_in, const int* in_sizes, int n_in,
                              void* d_out, int out_size, void* d_ws, size_t ws_size,
                              hipStream_t stream) {
  const float* x    = (const float*)d_in[0];
  const int*   val  = (const int*)d_in[1];
  const float* W    = (const float*)d_in[2];
  const float* lg   = (const float*)d_in[3];
  const float* attn = (const float*)d_in[4];
  const float* bias = (const float*)d_in[5];
  float* out = (float*)d_out;

  char* ws = (char*)d_ws;
  int* starts = (int*)(ws + 0);          // 11 ints
  u16* hist   = (u16*)(ws + 64);         // 128*10 u16
  int* perm   = (int*)(ws + 2688);       // 34048 ints -> ends 138880
  u16* weff   = (u16*)(ws + 139264);     // 10*512*512 bf16 = 5.24 MB

  k1<<<DD / 256 + NHB, 256, 0, stream>>>(W, lg, attn, val, weff, hist, perm);
  k2<<<NHB, 256, 0, stream>>>(val, hist, perm, starts);
  k3<<<dim3(D / TN, MAX_RT), 256, 0, stream>>>(x, weff, perm, starts, bias, out);
}

// Round 4
// 171.803 us; speedup vs baseline: 1.1125x; 1.0862x over previous
//
#include <hip/hip_runtime.h>

#define B_N 32768
#define D 512
#define DD (D * D)
#define NLEV 10
#define TM 128
#define TN 256
#define BK 32
#define NITER (D / BK)            // 16
#define NHB 128                   // histogram blocks (B_N / 256)
#define MROWS_MAX 34048           // 32768 + 10*128 padding headroom
#define MAX_RT (MROWS_MAX / TM)   // 266

typedef unsigned short u16;
typedef short s16x8 __attribute__((ext_vector_type(8)));
typedef u16 u16x8 __attribute__((ext_vector_type(8)));
typedef float f32x4 __attribute__((ext_vector_type(4)));

__device__ __forceinline__ u16 f2bf(float f) {
  union { float f; unsigned u; } v; v.f = f;
  unsigned r = v.u + 0x7fffu + ((v.u >> 16) & 1u);  // RNE
  return (u16)(r >> 16);
}
__device__ __forceinline__ int clampv(int v) {
  return v < 0 ? 0 : (v > NLEV - 1 ? NLEV - 1 : v);
}

// ---- K1: weff-build (blocks 0..1023) UNION hist+perm-fill (blocks 1024..1151)
__global__ void k1(const float* __restrict__ W, const float* __restrict__ lg,
                   const float* __restrict__ attn, const int* __restrict__ val,
                   u16* __restrict__ weff, u16* __restrict__ hist,
                   int* __restrict__ perm) {
  const int t = threadIdx.x;
  if (blockIdx.x < DD / 256) {
    __shared__ float c[NLEV * NLEV];
    if (t < NLEV) {
      float g[NLEV], a[NLEV], mx = -1e30f;
      #pragma unroll
      for (int l = 0; l < NLEV; ++l) {
        g[l] = 1.0f / (1.0f + expf(-lg[l]));
        a[l] = attn[t * NLEV + l];
        mx = fmaxf(mx, a[l]);
      }
      float s = 0.f;
      #pragma unroll
      for (int l = 0; l < NLEV; ++l) { a[l] = expf(a[l] - mx); s += a[l]; }
      float inv = 1.0f / s;
      #pragma unroll
      for (int l = 0; l < NLEV; ++l) {
        float cc = 0.3f * a[l] * inv * g[l];
        if (l == t) cc += 0.7f * g[t];
        c[t * NLEV + l] = cc;
      }
    }
    __syncthreads();
    const int idx = blockIdx.x * 256 + t;
    float w[NLEV];
    #pragma unroll
    for (int l = 0; l < NLEV; ++l) w[l] = W[l * DD + idx];
    #pragma unroll
    for (int v = 0; v < NLEV; ++v) {
      float s = 0.f;
      #pragma unroll
      for (int l = 0; l < NLEV; ++l) s += c[v * NLEV + l] * w[l];
      weff[v * DD + idx] = f2bf(s);
    }
  } else {
    __shared__ int lc[NLEV];
    const int b = blockIdx.x - DD / 256;   // 0..127
    if (t < NLEV) lc[t] = 0;
    __syncthreads();
    const int gid = b * 256 + t;
    atomicAdd(&lc[clampv(val[gid])], 1);
    perm[gid] = -1;
    if (b < (MROWS_MAX - B_N) / 256) perm[B_N + b * 256 + t] = -1;
    __syncthreads();
    if (t < NLEV) hist[b * NLEV + t] = (u16)lc[t];
  }
}

// ---- K2: deterministic counting-sort scatter (prefix over hist table) ------
__global__ void k2(const int* __restrict__ val, const u16* __restrict__ hist,
                   int* __restrict__ perm, int* __restrict__ starts) {
  __shared__ int h[NHB * NLEV];
  __shared__ int st[NLEV + 1];
  __shared__ int cnt[NLEV];
  __shared__ int lc[NLEV];
  const int t = threadIdx.x, b = blockIdx.x;
  for (int i = t; i < NHB * NLEV; i += 256) h[i] = hist[i];
  if (t < NLEV) lc[t] = 0;
  __syncthreads();
  if (t < NLEV) {
    int run = 0;
    for (int bb = 0; bb < NHB; ++bb) {
      int x = h[bb * NLEV + t];
      h[bb * NLEV + t] = run;
      run += x;
    }
    cnt[t] = run;
  }
  __syncthreads();
  if (t == 0) {
    int s = 0;
    for (int v = 0; v < NLEV; ++v) {
      st[v] = s;
      s += (cnt[v] + TM - 1) & ~(TM - 1);
    }
    st[NLEV] = s;
  }
  __syncthreads();
  const int gid = b * 256 + t;
  const int v = clampv(val[gid]);
  const int pos = atomicAdd(&lc[v], 1);
  perm[st[v] + h[b * NLEV + v] + pos] = gid;
  if (b == 0 && t <= NLEV) starts[t] = st[t];
}

// ---- K3: grouped GEMM, 128x256 tile, TRIPLE-buffered, counted-vmcnt -------
// R0 structure (best known: 67.7us, FETCH 78MB, 0 conflicts) with the
// vmcnt(0)-drain barrier replaced by: depth-2 B prefetch into 3 LDS buffers,
// raw s_barrier, hand-counted s_waitcnt vmcnt(4) so the newest 4 vmem ops
// (x(i+2) regs + B(i+2) gload_lds) stay in flight ACROSS the barrier.
// Prologue drains vmcnt(0) once (intrinsic-reorder safety; one-time cost).
__global__ __launch_bounds__(512, 4) void k3(
    const float* __restrict__ x, const u16* __restrict__ weff,
    const int* __restrict__ perm, const int* __restrict__ starts,
    const float* __restrict__ bias, float* __restrict__ out) {
  __shared__ u16 As[3][TM * BK];   // 3 x 8 KB
  __shared__ u16 Bs[3][TN * BK];   // 3 x 16 KB  -> 72 KB total, 2 blocks/CU

  const int ct = blockIdx.x, rt = blockIdx.y;
  const int Mpad = starts[NLEV];
  if (rt * TM >= Mpad) return;

  int v = 0;
  #pragma unroll
  for (int i = 1; i < NLEV; ++i) if (rt * TM >= starts[i]) v = i;

  const int tid = threadIdx.x;
  const int lane = tid & 63, wave = tid >> 6;
  const int wm = (wave >> 2) * 64, wn = (wave & 3) * 64;
  const int fm = lane & 15;
  const int cb = lane >> 4;

  // A staging: 4 threads per row, 8 floats (one 16B bf16 chunk) each
  const int ar = tid >> 2;       // 0..127
  const int ah = tid & 3;        // chunk 0..3
  int prow = perm[rt * TM + ar];
  if (prow < 0) prow = 0;
  const float* xrow = x + (size_t)prow * D + ah * 8;
  const int sw = (ar >> 1) & 3;
  const int aslot = ar * BK + ((ah ^ sw) << 3);

  const u16* wb = weff + ((size_t)v * D + ct * TN) * D;
  // B staging source addresses (two 16B chunks per thread), swizzled at source
  const int c0i = wave * 64 + lane;            // chunk id = n*4 + slot
  const int c1i = 512 + c0i;
  const int n0 = c0i >> 2, s0 = c0i & 3, kc0 = s0 ^ ((n0 >> 1) & 3);
  const int n1 = c1i >> 2, s1 = c1i & 3, kc1 = s1 ^ ((n1 >> 1) & 3);
  const u16* gb0 = wb + n0 * D + kc0 * 8;
  const u16* gb1 = wb + n1 * D + kc1 * 8;
  const int bdst0 = c0i * 8, bdst1 = c1i * 8;

  f32x4 acc[4][4];
  #pragma unroll
  for (int i = 0; i < 4; ++i)
    #pragma unroll
    for (int j = 0; j < 4; ++j) acc[i][j] = (f32x4){0.f, 0.f, 0.f, 0.f};

  // ---- prologue: A(0) direct, x(1)->cf, issue B(0) and B(1) ----
  {
    const f32x4* xp = (const f32x4*)xrow;
    f32x4 f0 = xp[0], f1 = xp[1];
    u16x8 cc;
    #pragma unroll
    for (int q = 0; q < 4; ++q) { cc[q] = f2bf(f0[q]); cc[4 + q] = f2bf(f1[q]); }
    *(u16x8*)(As[0] + aslot) = cc;
  }
  f32x4 cf0, cf1;   // x data for iter i+1
  {
    const f32x4* xp = (const f32x4*)(xrow + BK);
    cf0 = xp[0]; cf1 = xp[1];
  }
  __builtin_amdgcn_global_load_lds(
      (const __attribute__((address_space(1))) void*)gb0,
      (__attribute__((address_space(3))) void*)(Bs[0] + bdst0), 16, 0, 0);
  __builtin_amdgcn_global_load_lds(
      (const __attribute__((address_space(1))) void*)gb1,
      (__attribute__((address_space(3))) void*)(Bs[0] + bdst1), 16, 0, 0);
  __builtin_amdgcn_global_load_lds(
      (const __attribute__((address_space(1))) void*)(gb0 + BK),
      (__attribute__((address_space(3))) void*)(Bs[1] + bdst0), 16, 0, 0);
  __builtin_amdgcn_global_load_lds(
      (const __attribute__((address_space(1))) void*)(gb1 + BK),
      (__attribute__((address_space(3))) void*)(Bs[1] + bdst1), 16, 0, 0);
  // one-time full drain: intrinsic issue-order within this region is not
  // guaranteed, so a counted wait here is not provably safe. Cheap (once).
  asm volatile("s_waitcnt vmcnt(0)" ::: "memory");
  asm volatile("s_waitcnt lgkmcnt(0)" ::: "memory");   // A(0) ds_write visible
  __builtin_amdgcn_s_barrier();
  __builtin_amdgcn_sched_barrier(0);

  // rotating LDS buffer pointers
  u16 *Ar = (u16*)As[0], *Aw = (u16*)As[1], *Ax = (u16*)As[2];
  u16 *Br = (u16*)Bs[0], *Bm = (u16*)Bs[1], *Bw = (u16*)Bs[2];

  for (int i = 0; i < NITER; ++i) {
    const bool h2 = (i + 2 < NITER);
    const bool hn = (i + 1 < NITER);
    // issue x loads for iter i+2 (consumed at i+1's A-write)
    f32x4 nf0, nf1;
    if (h2) {
      const f32x4* xp = (const f32x4*)(xrow + (i + 2) * BK);
      nf0 = xp[0]; nf1 = xp[1];
    }
    // issue B prefetch for iter i+2 into Bw
    if (h2) {
      const int ko = (i + 2) * BK;
      __builtin_amdgcn_global_load_lds(
          (const __attribute__((address_space(1))) void*)(gb0 + ko),
          (__attribute__((address_space(3))) void*)(Bw + bdst0), 16, 0, 0);
      __builtin_amdgcn_global_load_lds(
          (const __attribute__((address_space(1))) void*)(gb1 + ko),
          (__attribute__((address_space(3))) void*)(Bw + bdst1), 16, 0, 0);
    }
    // compute on Ar/Br (B(i) landed: counted wait + barrier last iter)
    s16x8 af[4], bf[4];
    #pragma unroll
    for (int t4 = 0; t4 < 4; ++t4) {
      const int m = wm + t4 * 16 + fm;
      af[t4] = *(const s16x8*)(Ar + m * BK + ((cb ^ ((m >> 1) & 3)) << 3));
      const int n = wn + t4 * 16 + fm;
      bf[t4] = *(const s16x8*)(Br + n * BK + ((cb ^ ((n >> 1) & 3)) << 3));
    }
    __builtin_amdgcn_s_setprio(1);
    #pragma unroll
    for (int tm = 0; tm < 4; ++tm)
      #pragma unroll
      for (int tn = 0; tn < 4; ++tn)
        acc[tm][tn] = __builtin_amdgcn_mfma_f32_16x16x32_bf16(af[tm], bf[tn], acc[tm][tn], 0, 0, 0);
    __builtin_amdgcn_s_setprio(0);
    if (hn) {
      // convert + LDS-write the x chunk for iter i+1 (loaded 2 iters ago)
      u16x8 cc;
      #pragma unroll
      for (int q = 0; q < 4; ++q) { cc[q] = f2bf(cf0[q]); cc[4 + q] = f2bf(cf1[q]); }
      *(u16x8*)(Aw + aslot) = cc;
      if (h2) { cf0 = nf0; cf1 = nf1; }
      // counted pre-barrier wait: B(i+1) must have landed for THIS wave;
      // the barrier then orders it ahead of all waves' next-iter reads.
      // Iteration bodies are separated by asm memory clobbers, so the 4
      // newest outstanding vmem ops are exactly iter i's {x(i+2)x2,B(i+2)x2}.
      if (h2) asm volatile("s_waitcnt vmcnt(4)" ::: "memory");
      else    asm volatile("s_waitcnt vmcnt(0)" ::: "memory");
      asm volatile("s_waitcnt lgkmcnt(0)" ::: "memory");
      __builtin_amdgcn_s_barrier();
      __builtin_amdgcn_sched_barrier(0);
      // rotate buffers
      u16* t;
      t = Ar; Ar = Aw; Aw = Ax; Ax = t;
      t = Br; Br = Bm; Bm = Bw; Bw = t;
    }
  }

  // Epilogue: C frag col=lane&15, row=(lane>>4)*4+reg; scatter rows via perm
  float bv[4];
  #pragma unroll
  for (int tn = 0; tn < 4; ++tn) bv[tn] = bias[ct * TN + wn + tn * 16 + fm];
  #pragma unroll
  for (int tm = 0; tm < 4; ++tm) {
    #pragma unroll
    for (int r = 0; r < 4; ++r) {
      const int mrow = wm + tm * 16 + (lane >> 4) * 4 + r;
      const int p2 = perm[rt * TM + mrow];
      if (p2 >= 0) {
        float* o = out + (size_t)p2 * D + ct * TN + wn + fm;
        #pragma unroll
        for (int tn = 0; tn < 4; ++tn)
          o[tn * 16] = acc[tm][tn][r] + bv[tn];
      }
    }
  }
}

extern "C" void kernel_launch(void* const* d_in, const int* in_sizes, int n_in,
                              void* d_out, int out_size, void* d_ws, size_t ws_size,
                              hipStream_t stream) {
  const float* x    = (const float*)d_in[0];
  const int*   val  = (const int*)d_in[1];
  const float* W    = (const float*)d_in[2];
  const float* lg   = (const float*)d_in[3];
  const float* attn = (const float*)d_in[4];
  const float* bias = (const float*)d_in[5];
  float* out = (float*)d_out;

  char* ws = (char*)d_ws;
  int* starts = (int*)(ws + 0);          // 11 ints
  u16* hist   = (u16*)(ws + 64);         // 128*10 u16
  int* perm   = (int*)(ws + 2688);       // 34048 ints -> ends 138880
  u16* weff   = (u16*)(ws + 139264);     // 10*512*512 bf16 = 5.24 MB

  k1<<<DD / 256 + NHB, 256, 0, stream>>>(W, lg, attn, val, weff, hist, perm);
  k2<<<NHB, 256, 0, stream>>>(val, hist, perm, starts);
  k3<<<dim3(D / TN, MAX_RT), 512, 0, stream>>>(x, weff, perm, starts, bias, out);
}